// Round 20
// baseline (351.558 us; speedup 1.0000x reference)
//
#include <hip/hip_runtime.h>
#include <hip/hip_bf16.h>
#include <stdint.h>

#define BATCH  8192
#define NFEAT  8192
#define DMODEL 1024

typedef unsigned short u16;
typedef __attribute__((ext_vector_type(8))) short  short8;
typedef __attribute__((ext_vector_type(4))) float  f32x4;

// fp32 -> bf16 round-to-nearest-even
__device__ __forceinline__ u16 f2b(float f) {
    uint32_t u = __float_as_uint(f);
    u += 0x7fffu + ((u >> 16) & 1u);
    return (u16)(u >> 16);
}

// async global->LDS, 16B per lane; LDS dest is wave-uniform base + lane*16 (HW rule)
__device__ __forceinline__ void gld16(const u16* g, void* l) {
    __builtin_amdgcn_global_load_lds(
        (const __attribute__((address_space(1))) void*)(uintptr_t)g,
        (__attribute__((address_space(3))) void*)(uint32_t)(uintptr_t)l,
        16, 0, 0);
}

// ---------------- conversion kernels ----------------

__global__ void cvt_x_kernel(const float* __restrict__ x, u16* __restrict__ xb) {
    int i = blockIdx.x * blockDim.x + threadIdx.x;
    const float4* xv = (const float4*)x;
    float4 a = xv[2 * i];
    float4 b = xv[2 * i + 1];
    union { u16 u[8]; uint4 v; } o;
    o.u[0] = f2b(a.x); o.u[1] = f2b(a.y); o.u[2] = f2b(a.z); o.u[3] = f2b(a.w);
    o.u[4] = f2b(b.x); o.u[5] = f2b(b.y); o.u[6] = f2b(b.z); o.u[7] = f2b(b.w);
    ((uint4*)xb)[i] = o.v;
}

__global__ void cvt_w_kernel(const float* __restrict__ W,
                             u16* __restrict__ wb, u16* __restrict__ wt) {
    __shared__ u16 tile[64][65];
    const int f0 = blockIdx.x * 64;
    const int d0 = blockIdx.y * 64;
    const int t  = threadIdx.x;
#pragma unroll
    for (int rep = 0; rep < 16; ++rep) {
        int idx = rep * 256 + t;
        int r = idx >> 6, c = idx & 63;
        float v = W[(size_t)(f0 + r) * DMODEL + d0 + c];
        u16 u = f2b(v);
        tile[r][c] = u;
        wb[(size_t)(f0 + r) * DMODEL + d0 + c] = u;
    }
    __syncthreads();
#pragma unroll
    for (int rep = 0; rep < 16; ++rep) {
        int idx = rep * 256 + t;
        int r = idx >> 6, c = idx & 63;
        wt[(size_t)(d0 + r) * NFEAT + f0 + c] = tile[c][r];
    }
}

// compiler-level ordering fence (no instruction) + HW barrier
#define CBAR() do { asm volatile("" ::: "memory"); __builtin_amdgcn_s_barrier(); } while (0)

// LDS tile layout (verified conflict-free r13/14): row-major [rows][64] bf16 (128 B/row);
// 1-KB chunk = 8 rows. Stage: lane -> (row 8c+lane>>3, granule (lane&7)^(lane>>3)) = full
// 128-B lines. Read: phys granule ch0 = (lhi^(lane&7))<<4, k-slice at ch0^64.

// Shared macros for the 256x128 register-prefetch pipeline (gemm1_pipe).
#define PREF(T, A0P, BP) do {                                                   \
        if ((T) < NT) {                                                         \
            const char* Abp = lds + ((T) % 3) * 32768 + wm * 16384 + l15 * 128; \
            const char* Bbp = lds + BOFF + ((T) & 1) * 16384 + wn * 4096 + l15 * 128; \
            _Pragma("unroll")                                                   \
            for (int fm = 0; fm < 4; ++fm) {                                    \
                A0P[fm][0] = *(const short8*)(Abp + fm * 2048 + ch0);           \
                A0P[fm][1] = *(const short8*)(Abp + fm * 2048 + (ch0 ^ 64));    \
            }                                                                   \
            _Pragma("unroll")                                                   \
            for (int nh = 0; nh < 2; ++nh) {                                    \
                BP[nh][0] = *(const short8*)(Bbp + nh * 2048 + ch0);            \
                BP[nh][1] = *(const short8*)(Bbp + nh * 2048 + (ch0 ^ 64));     \
            }                                                                   \
        }                                                                       \
    } while (0)

#define MMA0_(A0C, BC) do {                                                     \
        _Pragma("unroll")                                                       \
        for (int nh = 0; nh < 2; ++nh)                                          \
            _Pragma("unroll")                                                   \
            for (int ks = 0; ks < 2; ++ks)                                      \
                _Pragma("unroll")                                               \
                for (int fm = 0; fm < 4; ++fm)                                  \
                    acc[fm][nh] = __builtin_amdgcn_mfma_f32_16x16x32_bf16(      \
                        A0C[fm][ks], BC[nh][ks], acc[fm][nh], 0, 0, 0);         \
    } while (0)

#define MMA1_(BC) do {                                                          \
        _Pragma("unroll")                                                       \
        for (int nh = 0; nh < 2; ++nh)                                          \
            _Pragma("unroll")                                                   \
            for (int ks = 0; ks < 2; ++ks)                                      \
                _Pragma("unroll")                                               \
                for (int fm = 0; fm < 4; ++fm)                                  \
                    acc[4 + fm][nh] = __builtin_amdgcn_mfma_f32_16x16x32_bf16(  \
                        a1[fm][ks], BC[nh][ks], acc[4 + fm][nh], 0, 0, 0);      \
    } while (0)

#define GTILE(T, A0C, BC, A0P, BP) do {                                         \
        const char* Ab_ = lds + ((T) % 3) * 32768 + wm * 16384 + l15 * 128;     \
        _Pragma("unroll")                                                       \
        for (int fm = 0; fm < 4; ++fm) {                                        \
            a1[fm][0] = *(const short8*)(Ab_ + (4 + fm) * 2048 + ch0);          \
            a1[fm][1] = *(const short8*)(Ab_ + (4 + fm) * 2048 + (ch0 ^ 64));   \
        }                                                                       \
        STAGE_A((T) + 2);                                                       \
        __builtin_amdgcn_s_setprio(1);                                          \
        MMA0_(A0C, BC);                                                         \
        __builtin_amdgcn_s_setprio(0);                                          \
        STAGE_B((T) + 2);                                                       \
        if ((T) < NT - 2) asm volatile("s_waitcnt vmcnt(6)" ::: "memory");      \
        else              asm volatile("s_waitcnt vmcnt(0)" ::: "memory");      \
        CBAR();   /* all waves: (T+1) landed -> prefetch reads safe */          \
        PREF((T) + 1, A0P, BP);                                                 \
        __builtin_amdgcn_s_setprio(1);                                          \
        MMA1_(BC);                                                              \
        __builtin_amdgcn_s_setprio(0);                                          \
    } while (0)

// ---------------- GEMM 1: 256x128 tile, register-prefetch pipeline (round-16 best) ---------
// H = A @ B^T (bf16). Grid 256. LDS 128 KiB: A 3x32K @0, B 2x16K @98304.
__global__ __launch_bounds__(512, 2)
void gemm1_pipe(const u16* __restrict__ A, const u16* __restrict__ B,
                u16* __restrict__ H, int N, int K) {
    const int NT = K >> 6;                 // 128
    __shared__ __align__(1024) char lds[131072];
    const int BOFF = 98304;

    const int tid  = threadIdx.x;
    const int lane = tid & 63;
    const int wave = tid >> 6;
    const int wm   = wave >> 2;
    const int wn   = wave & 3;

    const int nwg = gridDim.x;
    const int swz = (blockIdx.x & 7) * (nwg >> 3) + (blockIdx.x >> 3);
    const int ntn = N >> 7;
    const int tm0 = (swz / ntn) << 8;
    const int tn0 = (swz % ntn) << 7;

    const int sr8 = lane >> 3;
    const int sg  = (lane & 7) ^ sr8;
    const int l15 = lane & 15, lhi = lane >> 4;
    const int ch0 = ((lhi ^ (lane & 7)) << 4);

    auto STAGE_A = [&](int tau) {
        if (tau < NT) {
            char* d = lds + (tau % 3) * 32768 + wave * 4096;
#pragma unroll
            for (int i = 0; i < 4; ++i)
                gld16(A + (size_t)(tm0 + wave * 32 + i * 8 + sr8) * K + ((size_t)tau << 6) + sg * 8,
                      d + i * 1024);
        }
    };
    auto STAGE_B = [&](int tau) {
        if (tau < NT) {
            char* d = lds + BOFF + (tau & 1) * 16384 + wave * 2048;
#pragma unroll
            for (int i = 0; i < 2; ++i)
                gld16(B + (size_t)(tn0 + wave * 16 + i * 8 + sr8) * K + ((size_t)tau << 6) + sg * 8,
                      d + i * 1024);
        }
    };

    short8 a0X[4][2], a0Y[4][2], a1[4][2];
    short8 bX[2][2], bY[2][2];
    f32x4  acc[8][2] = {};

    STAGE_A(0); STAGE_B(0);
    STAGE_A(1); STAGE_B(1);
    asm volatile("s_waitcnt vmcnt(6)" ::: "memory");
    __builtin_amdgcn_s_barrier();
    PREF(0, a0X, bX);

    for (int t = 0; t < NT; t += 2) {
        GTILE(t,     a0X, bX, a0Y, bY);
        GTILE(t + 1, a0Y, bY, a0X, bX);
    }
    __syncthreads();   // 1-barrier loop: sync before LDS reuse in epilogue

    // epilogue: bf16 tile via LDS transpose, coalesced 16B stores
    u16* lu = (u16*)lds;
#pragma unroll
    for (int fm = 0; fm < 8; ++fm)
#pragma unroll
        for (int nh = 0; nh < 2; ++nh) {
            const int col  = wn * 32 + nh * 16 + l15;
            const int row0 = wm * 128 + fm * 16 + lhi * 4;
#pragma unroll
            for (int r = 0; r < 4; ++r)
                lu[(row0 + r) * 128 + col] = f2b(acc[fm][nh][r]);
        }
    __syncthreads();
    const uint4* ls = (const uint4*)lds;
#pragma unroll
    for (int s = 0; s < 8; ++s) {
        int i = s * 512 + tid;
        int row = i >> 4;
        int col = (i & 15) * 8;
        *(uint4*)(H + (size_t)(tm0 + row) * N + (tn0 + col)) = ls[i];
    }
}

// ---------------- GEMM 2: persistent 1024x256 panels + boundary vmcnt(63) ----------------
// out = relu(A @ B^T + bias), fp32. Grid 256 (1/CU), 4 chained 256x256 tiles,
// continuous tau pipeline. LDS 160 KiB: A 3x32K @0, B 2x32K @98304.
// NEW: at the post-epilogue K-step (tt = 16/32/48) the tile-end wait is vmcnt(63):
// queue = [loads(t+1) 8, stores 128, loads(t+2) 8] = 144; retiring to 63 proves the
// (t+1) loads landed while leaving 55 stores in flight to drain under the next K-step.
__global__ __launch_bounds__(512, 2)
void gemm2_persist(const u16* __restrict__ A, const u16* __restrict__ B,
                   float* __restrict__ O, const float* __restrict__ bias,
                   int N, int K) {
    __shared__ __align__(1024) char lds[163840];
    const int BOFF = 98304;
    const int TTOT = 64;

    const int tid  = threadIdx.x;
    const int lane = tid & 63;
    const int wave = tid >> 6;
    const int wm   = wave >> 2;
    const int wn   = wave & 3;

    const int bid = blockIdx.x;
    const int xcd = bid & 7;
    const int sub = (bid >> 3) & 3;
    const int mg  = bid >> 5;
    const int tn0     = ((xcd << 2) + sub) << 8;
    const int tm_base = mg << 10;

    const int sr8 = lane >> 3;
    const int sg  = (lane & 7) ^ sr8;
    const int l15 = lane & 15, lhi = lane >> 4;
    const int ch0 = ((lhi ^ (lane & 7)) << 4);

    auto STAGE_A = [&](int tau) {
        if (tau < TTOT) {
            char* d = lds + (tau % 3) * 32768 + wave * 4096;
            const int rb = tm_base + ((tau >> 4) << 8) + wave * 32 + sr8;
            const size_t co = ((size_t)(tau & 15) << 6) + sg * 8;
#pragma unroll
            for (int i = 0; i < 4; ++i)
                gld16(A + (size_t)(rb + i * 8) * K + co, d + i * 1024);
        }
    };
    auto STAGE_B = [&](int tau) {
        if (tau < TTOT) {
            char* d = lds + BOFF + (tau & 1) * 32768 + wave * 4096;
            const int rb = tn0 + wave * 32 + sr8;
            const size_t co = ((size_t)(tau & 15) << 6) + sg * 8;
#pragma unroll
            for (int i = 0; i < 4; ++i)
                gld16(B + (size_t)(rb + i * 8) * K + co, d + i * 1024);
        }
    };

    short8 a0[4][2], a1[4][2];
    short8 b[4][2];
    f32x4  acc[8][4] = {};

    const char* Ab;
    const char* Bb;
    auto LDA0 = [&] {
#pragma unroll
        for (int fm = 0; fm < 4; ++fm) {
            a0[fm][0] = *(const short8*)(Ab + fm * 2048 + ch0);
            a0[fm][1] = *(const short8*)(Ab + fm * 2048 + (ch0 ^ 64));
        }
    };
    auto LDA1 = [&] {
#pragma unroll
        for (int fm = 0; fm < 4; ++fm) {
            a1[fm][0] = *(const short8*)(Ab + (4 + fm) * 2048 + ch0);
            a1[fm][1] = *(const short8*)(Ab + (4 + fm) * 2048 + (ch0 ^ 64));
        }
    };
    auto LDB_ = [&](int nh) {
#pragma unroll
        for (int fn = 0; fn < 2; ++fn) {
            b[nh * 2 + fn][0] = *(const short8*)(Bb + (nh * 2 + fn) * 2048 + ch0);
            b[nh * 2 + fn][1] = *(const short8*)(Bb + (nh * 2 + fn) * 2048 + (ch0 ^ 64));
        }
    };
    auto MMA0 = [&](int nh) {
#pragma unroll
        for (int ks = 0; ks < 2; ++ks)
#pragma unroll
            for (int fm = 0; fm < 4; ++fm)
#pragma unroll
                for (int fn = 0; fn < 2; ++fn)
                    acc[fm][nh * 2 + fn] = __builtin_amdgcn_mfma_f32_16x16x32_bf16(
                        a0[fm][ks], b[nh * 2 + fn][ks], acc[fm][nh * 2 + fn], 0, 0, 0);
    };
    auto MMA1 = [&](int nh) {
#pragma unroll
        for (int ks = 0; ks < 2; ++ks)
#pragma unroll
            for (int fm = 0; fm < 4; ++fm)
#pragma unroll
                for (int fn = 0; fn < 2; ++fn)
                    acc[4 + fm][nh * 2 + fn] = __builtin_amdgcn_mfma_f32_16x16x32_bf16(
                        a1[fm][ks], b[nh * 2 + fn][ks], acc[4 + fm][nh * 2 + fn], 0, 0, 0);
    };

    const int ocol = tn0 + wn * 64;
    float bv[4];
#pragma unroll
    for (int fn = 0; fn < 4; ++fn) bv[fn] = bias[ocol + fn * 16 + l15];

    STAGE_A(0); STAGE_B(0);
    STAGE_A(1); STAGE_B(1);
    asm volatile("s_waitcnt vmcnt(8)" ::: "memory");
    __builtin_amdgcn_s_barrier();

    for (int tt = 0; tt < TTOT; ++tt) {
        Ab = lds + (tt % 3) * 32768 + wm * 16384 + l15 * 128;
        Bb = lds + BOFF + (tt & 1) * 32768 + wn * 8192 + l15 * 128;

        LDB_(0); LDB_(1); LDA0(); LDA1();
        STAGE_A(tt + 2);
        __builtin_amdgcn_s_setprio(1);
        MMA0(0); MMA0(1);
        __builtin_amdgcn_s_setprio(0);
        CBAR();                    // B reads drained (consumed above); safe to restage B
        STAGE_B(tt + 2);
        __builtin_amdgcn_s_setprio(1);
        MMA1(1); MMA1(0);
        __builtin_amdgcn_s_setprio(0);
        if (tt == TTOT - 2) {
            asm volatile("s_waitcnt vmcnt(0)" ::: "memory");
        } else if (tt < TTOT - 2) {
            if ((tt & 15) == 0 && tt > 0) {
                // post-epilogue boundary: keep stores in flight, retire only the
                // 8 loads of tile (tt+1) plus the oldest stores (in-order proof)
                asm volatile("s_waitcnt vmcnt(63)" ::: "memory");
            } else {
                asm volatile("s_waitcnt vmcnt(8)" ::: "memory");
            }
        }
        CBAR();

        // per-tile epilogue after the barrier: stores overlap next tile's K-loop
        if ((tt & 15) == 15) {
            const int orow = tm_base + ((tt >> 4) << 8) + wm * 128;
#pragma unroll
            for (int fm = 0; fm < 8; ++fm) {
                const int row0 = orow + fm * 16 + lhi * 4;
#pragma unroll
                for (int fn = 0; fn < 4; ++fn) {
                    const int col = ocol + fn * 16 + l15;
#pragma unroll
                    for (int r = 0; r < 4; ++r) {
                        float v = acc[fm][fn][r] + bv[fn];
                        O[(size_t)(row0 + r) * N + col] = v > 0.f ? v : 0.f;
                        acc[fm][fn][r] = 0.f;
                    }
                }
            }
        }
    }
}

// ---------------- launch ----------------

extern "C" void kernel_launch(void* const* d_in, const int* in_sizes, int n_in,
                              void* d_out, int out_size, void* d_ws, size_t ws_size,
                              hipStream_t stream) {
    const float* x    = (const float*)d_in[0];   // [8192, 8192]
    const float* W    = (const float*)d_in[1];   // [8192, 1024]
    const float* bias = (const float*)d_in[2];   // [8192]
    float* out = (float*)d_out;                  // [8192, 8192] fp32

    char* ws = (char*)d_ws;
    u16* xb = (u16*)ws;                                        // 134217728 B
    u16* wt = (u16*)(ws + 134217728);                          // [1024][8192]
    u16* wb = (u16*)(ws + 134217728 + 16777216);               // [8192][1024]
    u16* hb = (u16*)(ws + 134217728 + 2 * 16777216);           // [8192][1024]

    cvt_x_kernel<<<(BATCH * NFEAT / 8) / 256, 256, 0, stream>>>(x, xb);
    cvt_w_kernel<<<dim3(NFEAT / 64, DMODEL / 64), 256, 0, stream>>>(W, wb, wt);

    gemm1_pipe<<<dim3((BATCH / 256) * (DMODEL / 128)), 512, 0, stream>>>(
        xb, wt, hb, DMODEL, NFEAT);

    gemm2_persist<<<dim3(256), 512, 0, stream>>>(
        hb, wb, out, bias, NFEAT, DMODEL);
}

// Round 21
// 350.347 us; speedup vs baseline: 1.0035x; 1.0035x over previous
//
#include <hip/hip_runtime.h>
#include <hip/hip_bf16.h>
#include <stdint.h>

#define BATCH  8192
#define NFEAT  8192
#define DMODEL 1024

typedef unsigned short u16;
typedef __attribute__((ext_vector_type(8))) short  short8;
typedef __attribute__((ext_vector_type(4))) float  f32x4;

// fp32 -> bf16 round-to-nearest-even
__device__ __forceinline__ u16 f2b(float f) {
    uint32_t u = __float_as_uint(f);
    u += 0x7fffu + ((u >> 16) & 1u);
    return (u16)(u >> 16);
}

// async global->LDS, 16B per lane; LDS dest is wave-uniform base + lane*16 (HW rule)
__device__ __forceinline__ void gld16(const u16* g, void* l) {
    __builtin_amdgcn_global_load_lds(
        (const __attribute__((address_space(1))) void*)(uintptr_t)g,
        (__attribute__((address_space(3))) void*)(uint32_t)(uintptr_t)l,
        16, 0, 0);
}

// ---------------- conversion kernels ----------------

__global__ void cvt_x_kernel(const float* __restrict__ x, u16* __restrict__ xb) {
    int i = blockIdx.x * blockDim.x + threadIdx.x;
    const float4* xv = (const float4*)x;
    float4 a = xv[2 * i];
    float4 b = xv[2 * i + 1];
    union { u16 u[8]; uint4 v; } o;
    o.u[0] = f2b(a.x); o.u[1] = f2b(a.y); o.u[2] = f2b(a.z); o.u[3] = f2b(a.w);
    o.u[4] = f2b(b.x); o.u[5] = f2b(b.y); o.u[6] = f2b(b.z); o.u[7] = f2b(b.w);
    ((uint4*)xb)[i] = o.v;
}

__global__ void cvt_w_kernel(const float* __restrict__ W,
                             u16* __restrict__ wb, u16* __restrict__ wt) {
    __shared__ u16 tile[64][65];
    const int f0 = blockIdx.x * 64;
    const int d0 = blockIdx.y * 64;
    const int t  = threadIdx.x;
#pragma unroll
    for (int rep = 0; rep < 16; ++rep) {
        int idx = rep * 256 + t;
        int r = idx >> 6, c = idx & 63;
        float v = W[(size_t)(f0 + r) * DMODEL + d0 + c];
        u16 u = f2b(v);
        tile[r][c] = u;
        wb[(size_t)(f0 + r) * DMODEL + d0 + c] = u;
    }
    __syncthreads();
#pragma unroll
    for (int rep = 0; rep < 16; ++rep) {
        int idx = rep * 256 + t;
        int r = idx >> 6, c = idx & 63;
        wt[(size_t)(d0 + r) * NFEAT + f0 + c] = tile[c][r];
    }
}

// compiler-level ordering fence (no instruction) + HW barrier
#define CBAR() do { asm volatile("" ::: "memory"); __builtin_amdgcn_s_barrier(); } while (0)

// LDS tile layout (verified conflict-free r13/14): row-major [rows][64] bf16 (128 B/row);
// 1-KB chunk = 8 rows. Stage: lane -> (row 8c+lane>>3, granule (lane&7)^(lane>>3)) = full
// 128-B lines. Read: phys granule ch0 = (lhi^(lane&7))<<4, k-slice at ch0^64.

// ---- shared MMA macros (acc[8][2], a1[4][2]) ----
#define MMA0_(A0C, BC) do {                                                     \
        _Pragma("unroll")                                                       \
        for (int nh = 0; nh < 2; ++nh)                                          \
            _Pragma("unroll")                                                   \
            for (int ks = 0; ks < 2; ++ks)                                      \
                _Pragma("unroll")                                               \
                for (int fm = 0; fm < 4; ++fm)                                  \
                    acc[fm][nh] = __builtin_amdgcn_mfma_f32_16x16x32_bf16(      \
                        A0C[fm][ks], BC[nh][ks], acc[fm][nh], 0, 0, 0);         \
    } while (0)

#define MMA1_(BC) do {                                                          \
        _Pragma("unroll")                                                       \
        for (int nh = 0; nh < 2; ++nh)                                          \
            _Pragma("unroll")                                                   \
            for (int ks = 0; ks < 2; ++ks)                                      \
                _Pragma("unroll")                                               \
                for (int fm = 0; fm < 4; ++fm)                                  \
                    acc[4 + fm][nh] = __builtin_amdgcn_mfma_f32_16x16x32_bf16(  \
                        a1[fm][ks], BC[nh][ks], acc[4 + fm][nh], 0, 0, 0);      \
    } while (0)

// ---- gemm1 macros (512 thr, A slots 32K, B slots 16K) ----
#define PREF(T, A0P, BP) do {                                                   \
        if ((T) < NT) {                                                         \
            const char* Abp = lds + ((T) % 3) * 32768 + wm * 16384 + l15 * 128; \
            const char* Bbp = lds + BOFF + ((T) & 1) * 16384 + wn * 4096 + l15 * 128; \
            _Pragma("unroll")                                                   \
            for (int fm = 0; fm < 4; ++fm) {                                    \
                A0P[fm][0] = *(const short8*)(Abp + fm * 2048 + ch0);           \
                A0P[fm][1] = *(const short8*)(Abp + fm * 2048 + (ch0 ^ 64));    \
            }                                                                   \
            _Pragma("unroll")                                                   \
            for (int nh = 0; nh < 2; ++nh) {                                    \
                BP[nh][0] = *(const short8*)(Bbp + nh * 2048 + ch0);            \
                BP[nh][1] = *(const short8*)(Bbp + nh * 2048 + (ch0 ^ 64));     \
            }                                                                   \
        }                                                                       \
    } while (0)

#define GTILE(T, A0C, BC, A0P, BP) do {                                         \
        const char* Ab_ = lds + ((T) % 3) * 32768 + wm * 16384 + l15 * 128;     \
        _Pragma("unroll")                                                       \
        for (int fm = 0; fm < 4; ++fm) {                                        \
            a1[fm][0] = *(const short8*)(Ab_ + (4 + fm) * 2048 + ch0);          \
            a1[fm][1] = *(const short8*)(Ab_ + (4 + fm) * 2048 + (ch0 ^ 64));   \
        }                                                                       \
        STAGE_A((T) + 2);                                                       \
        __builtin_amdgcn_s_setprio(1);                                          \
        MMA0_(A0C, BC);                                                         \
        __builtin_amdgcn_s_setprio(0);                                          \
        STAGE_B((T) + 2);                                                       \
        if ((T) < NT - 2) asm volatile("s_waitcnt vmcnt(6)" ::: "memory");      \
        else              asm volatile("s_waitcnt vmcnt(0)" ::: "memory");      \
        CBAR();                                                                 \
        PREF((T) + 1, A0P, BP);                                                 \
        __builtin_amdgcn_s_setprio(1);                                          \
        MMA1_(BC);                                                              \
        __builtin_amdgcn_s_setprio(0);                                          \
    } while (0)

// ---------------- GEMM 1: 256x128 tile, register-prefetch pipeline (round-16 best) ---------
// H = A @ B^T (bf16). Grid 256. LDS 128 KiB: A 3x32K @0, B 2x16K @98304.
__global__ __launch_bounds__(512, 2)
void gemm1_pipe(const u16* __restrict__ A, const u16* __restrict__ B,
                u16* __restrict__ H, int N, int K) {
    const int NT = K >> 6;                 // 128
    __shared__ __align__(1024) char lds[131072];
    const int BOFF = 98304;

    const int tid  = threadIdx.x;
    const int lane = tid & 63;
    const int wave = tid >> 6;
    const int wm   = wave >> 2;
    const int wn   = wave & 3;

    const int nwg = gridDim.x;
    const int swz = (blockIdx.x & 7) * (nwg >> 3) + (blockIdx.x >> 3);
    const int ntn = N >> 7;
    const int tm0 = (swz / ntn) << 8;
    const int tn0 = (swz % ntn) << 7;

    const int sr8 = lane >> 3;
    const int sg  = (lane & 7) ^ sr8;
    const int l15 = lane & 15, lhi = lane >> 4;
    const int ch0 = ((lhi ^ (lane & 7)) << 4);

    auto STAGE_A = [&](int tau) {
        if (tau < NT) {
            char* d = lds + (tau % 3) * 32768 + wave * 4096;
#pragma unroll
            for (int i = 0; i < 4; ++i)
                gld16(A + (size_t)(tm0 + wave * 32 + i * 8 + sr8) * K + ((size_t)tau << 6) + sg * 8,
                      d + i * 1024);
        }
    };
    auto STAGE_B = [&](int tau) {
        if (tau < NT) {
            char* d = lds + BOFF + (tau & 1) * 16384 + wave * 2048;
#pragma unroll
            for (int i = 0; i < 2; ++i)
                gld16(B + (size_t)(tn0 + wave * 16 + i * 8 + sr8) * K + ((size_t)tau << 6) + sg * 8,
                      d + i * 1024);
        }
    };

    short8 a0X[4][2], a0Y[4][2], a1[4][2];
    short8 bX[2][2], bY[2][2];
    f32x4  acc[8][2] = {};

    STAGE_A(0); STAGE_B(0);
    STAGE_A(1); STAGE_B(1);
    asm volatile("s_waitcnt vmcnt(6)" ::: "memory");
    __builtin_amdgcn_s_barrier();
    PREF(0, a0X, bX);

    for (int t = 0; t < NT; t += 2) {
        GTILE(t,     a0X, bX, a0Y, bY);
        GTILE(t + 1, a0Y, bY, a0X, bX);
    }
    __syncthreads();   // 1-barrier loop: sync before LDS reuse in epilogue

    // epilogue: bf16 tile via LDS transpose, coalesced 16B stores
    u16* lu = (u16*)lds;
#pragma unroll
    for (int fm = 0; fm < 8; ++fm)
#pragma unroll
        for (int nh = 0; nh < 2; ++nh) {
            const int col  = wn * 32 + nh * 16 + l15;
            const int row0 = wm * 128 + fm * 16 + lhi * 4;
#pragma unroll
            for (int r = 0; r < 4; ++r)
                lu[(row0 + r) * 128 + col] = f2b(acc[fm][nh][r]);
        }
    __syncthreads();
    const uint4* ls = (const uint4*)lds;
#pragma unroll
    for (int s = 0; s < 8; ++s) {
        int i = s * 512 + tid;
        int row = i >> 4;
        int col = (i & 15) * 8;
        *(uint4*)(H + (size_t)(tm0 + row) * N + (tn0 + col)) = ls[i];
    }
}

// ---- gemm2 macros (256 thr, A slots 16K, B slots 16K) ----
#define PREF2(T, A0P, BP) do {                                                  \
        if ((T) < NT) {                                                         \
            const char* Abp = lds + ((T) % 3) * 16384 + l15 * 128;              \
            const char* Bbp = lds + BOFF + ((T) & 1) * 16384 + wn * 4096 + l15 * 128; \
            _Pragma("unroll")                                                   \
            for (int fm = 0; fm < 4; ++fm) {                                    \
                A0P[fm][0] = *(const short8*)(Abp + fm * 2048 + ch0);           \
                A0P[fm][1] = *(const short8*)(Abp + fm * 2048 + (ch0 ^ 64));    \
            }                                                                   \
            _Pragma("unroll")                                                   \
            for (int nh = 0; nh < 2; ++nh) {                                    \
                BP[nh][0] = *(const short8*)(Bbp + nh * 2048 + ch0);            \
                BP[nh][1] = *(const short8*)(Bbp + nh * 2048 + (ch0 ^ 64));     \
            }                                                                   \
        }                                                                       \
    } while (0)

#define GTILE2(T, A0C, BC, A0P, BP) do {                                        \
        const char* Ab_ = lds + ((T) % 3) * 16384 + l15 * 128;                  \
        _Pragma("unroll")                                                       \
        for (int fm = 0; fm < 4; ++fm) {                                        \
            a1[fm][0] = *(const short8*)(Ab_ + (4 + fm) * 2048 + ch0);          \
            a1[fm][1] = *(const short8*)(Ab_ + (4 + fm) * 2048 + (ch0 ^ 64));   \
        }                                                                       \
        STAGE_A((T) + 2);                                                       \
        __builtin_amdgcn_s_setprio(1);                                          \
        MMA0_(A0C, BC);                                                         \
        __builtin_amdgcn_s_setprio(0);                                          \
        STAGE_B((T) + 2);                                                       \
        if ((T) < NT - 2) asm volatile("s_waitcnt vmcnt(8)" ::: "memory");      \
        else              asm volatile("s_waitcnt vmcnt(0)" ::: "memory");      \
        CBAR();                                                                 \
        PREF2((T) + 1, A0P, BP);                                                \
        __builtin_amdgcn_s_setprio(1);                                          \
        MMA1_(BC);                                                              \
        __builtin_amdgcn_s_setprio(0);                                          \
    } while (0)

// ---------------- GEMM 2: 128x128 tile, 4 waves, 2 blocks/CU, persistent panels ------------
// out = relu(A @ B^T + bias), fp32. A = hb [8192][1024], B = wb [8192][1024].
// Grid 512 (2 blocks/CU -> two INDEPENDENT barrier domains per CU: one block's MFMA
// covers the other's barrier/vmcnt/store stalls). Each block owns a 1024x128 panel =
// 8 chained 128x128 tiles, continuous tau = 0..127 K-step stream.
// Wave split 1Mx4N: per-wave acc[8][2] = 64 AGPR -> gemm1-proven register prefetch fits.
// LDS 80 KiB: A 3x16K @0, B 2x16K @49152. Per-segment direct stores (drain hidden by
// the sibling block). XCD map: xcd owns 8 col panels (B slice 2 MB, L2-resident).
__global__ __launch_bounds__(256, 2)
void gemm2_pipe2(const u16* __restrict__ A, const u16* __restrict__ B,
                 float* __restrict__ O, const float* __restrict__ bias,
                 int N, int K) {
    const int NT = 128;                    // 8 segments x 16 K-steps
    __shared__ __align__(1024) char lds[81920];
    const int BOFF = 49152;

    const int tid  = threadIdx.x;
    const int lane = tid & 63;
    const int wave = tid >> 6;             // 0..3
    const int wn   = wave;                 // 1M x 4N: each wave = 32-col group

    const int bid = blockIdx.x;            // 512 = 8 xcd x 8 sub x 8 mg
    const int cp  = ((bid & 7) << 3) | ((bid >> 3) & 7);   // col panel 0..63
    const int mg  = (bid >> 6) & 7;                        // row group 0..7
    const int tn0     = cp << 7;                           // 128-col panel
    const int tm_base = mg << 10;                          // 1024-row group

    const int sr8 = lane >> 3;
    const int sg  = (lane & 7) ^ sr8;
    const int l15 = lane & 15, lhi = lane >> 4;
    const int ch0 = ((lhi ^ (lane & 7)) << 4);

    auto STAGE_A = [&](int tau) {          // 16 KiB tile, 256 thr -> 4 gld16
        if (tau < NT) {
            char* d = lds + (tau % 3) * 16384 + wave * 4096;
            const int rb = tm_base + ((tau >> 4) << 7) + wave * 32 + sr8;
            const size_t co = ((size_t)(tau & 15) << 6) + sg * 8;
#pragma unroll
            for (int i = 0; i < 4; ++i)
                gld16(A + (size_t)(rb + i * 8) * K + co, d + i * 1024);
        }
    };
    auto STAGE_B = [&](int tau) {          // 16 KiB tile, 256 thr -> 4 gld16
        if (tau < NT) {
            char* d = lds + BOFF + (tau & 1) * 16384 + wave * 4096;
            const int rb = tn0 + wave * 32 + sr8;
            const size_t co = ((size_t)(tau & 15) << 6) + sg * 8;
#pragma unroll
            for (int i = 0; i < 4; ++i)
                gld16(B + (size_t)(rb + i * 8) * K + co, d + i * 1024);
        }
    };

    short8 a0X[4][2], a0Y[4][2], a1[4][2];
    short8 bX[2][2], bY[2][2];
    f32x4  acc[8][2] = {};

    const int ocol = tn0 + wn * 32;
    float bv[2];
#pragma unroll
    for (int nh = 0; nh < 2; ++nh) bv[nh] = bias[ocol + nh * 16 + l15];

    // prologue: tiles 0,1 staged (16 loads); drain tile 0 (keep tile 1's 8)
    STAGE_A(0); STAGE_B(0);
    STAGE_A(1); STAGE_B(1);
    asm volatile("s_waitcnt vmcnt(8)" ::: "memory");
    __builtin_amdgcn_s_barrier();
    PREF2(0, a0X, bX);

    for (int t = 0; t < NT; t += 2) {
        GTILE2(t,     a0X, bX, a0Y, bY);
        GTILE2(t + 1, a0Y, bY, a0X, bX);

        // per-segment epilogue: direct fp32 relu+bias stores; drain overlapped by
        // the sibling block on this CU (independent barrier domain)
        if (((t + 1) & 15) == 15) {
            const int orow = tm_base + (((t + 1) >> 4) << 7);
#pragma unroll
            for (int fm = 0; fm < 8; ++fm) {
                const int row0 = orow + fm * 16 + lhi * 4;
#pragma unroll
                for (int nh = 0; nh < 2; ++nh) {
                    const int col = ocol + nh * 16 + l15;
#pragma unroll
                    for (int r = 0; r < 4; ++r) {
                        float v = acc[fm][nh][r] + bv[nh];
                        O[(size_t)(row0 + r) * N + col] = v > 0.f ? v : 0.f;
                        acc[fm][nh][r] = 0.f;
                    }
                }
            }
        }
    }
}

#undef GTILE
#undef GTILE2
#undef PREF
#undef PREF2
#undef MMA0_
#undef MMA1_

// ---------------- launch ----------------

extern "C" void kernel_launch(void* const* d_in, const int* in_sizes, int n_in,
                              void* d_out, int out_size, void* d_ws, size_t ws_size,
                              hipStream_t stream) {
    const float* x    = (const float*)d_in[0];   // [8192, 8192]
    const float* W    = (const float*)d_in[1];   // [8192, 1024]
    const float* bias = (const float*)d_in[2];   // [8192]
    float* out = (float*)d_out;                  // [8192, 8192] fp32

    char* ws = (char*)d_ws;
    u16* xb = (u16*)ws;                                        // 134217728 B
    u16* wt = (u16*)(ws + 134217728);                          // [1024][8192]
    u16* wb = (u16*)(ws + 134217728 + 16777216);               // [8192][1024]
    u16* hb = (u16*)(ws + 134217728 + 2 * 16777216);           // [8192][1024]

    cvt_x_kernel<<<(BATCH * NFEAT / 8) / 256, 256, 0, stream>>>(x, xb);
    cvt_w_kernel<<<dim3(NFEAT / 64, DMODEL / 64), 256, 0, stream>>>(W, wb, wt);

    gemm1_pipe<<<dim3((BATCH / 256) * (DMODEL / 128)), 512, 0, stream>>>(
        xb, wt, hb, DMODEL, NFEAT);

    // 512 blocks = 2/CU: two independent barrier domains per CU
    gemm2_pipe2<<<dim3(512), 256, 0, stream>>>(
        hb, wb, out, bias, NFEAT, DMODEL);
}

// Round 22
// 344.338 us; speedup vs baseline: 1.0210x; 1.0174x over previous
//
#include <hip/hip_runtime.h>
#include <hip/hip_bf16.h>
#include <stdint.h>

#define BATCH  8192
#define NFEAT  8192
#define DMODEL 1024

typedef unsigned short u16;
typedef __attribute__((ext_vector_type(8))) short  short8;
typedef __attribute__((ext_vector_type(4))) float  f32x4;

// fp32 -> bf16 round-to-nearest-even
__device__ __forceinline__ u16 f2b(float f) {
    uint32_t u = __float_as_uint(f);
    u += 0x7fffu + ((u >> 16) & 1u);
    return (u16)(u >> 16);
}

// async global->LDS, 16B per lane; LDS dest is wave-uniform base + lane*16 (HW rule)
__device__ __forceinline__ void gld16(const u16* g, void* l) {
    __builtin_amdgcn_global_load_lds(
        (const __attribute__((address_space(1))) void*)(uintptr_t)g,
        (__attribute__((address_space(3))) void*)(uint32_t)(uintptr_t)l,
        16, 0, 0);
}

// ---------------- conversion kernels ----------------

__global__ void cvt_x_kernel(const float* __restrict__ x, u16* __restrict__ xb) {
    int i = blockIdx.x * blockDim.x + threadIdx.x;
    const float4* xv = (const float4*)x;
    float4 a = xv[2 * i];
    float4 b = xv[2 * i + 1];
    union { u16 u[8]; uint4 v; } o;
    o.u[0] = f2b(a.x); o.u[1] = f2b(a.y); o.u[2] = f2b(a.z); o.u[3] = f2b(a.w);
    o.u[4] = f2b(b.x); o.u[5] = f2b(b.y); o.u[6] = f2b(b.z); o.u[7] = f2b(b.w);
    ((uint4*)xb)[i] = o.v;
}

__global__ void cvt_w_kernel(const float* __restrict__ W,
                             u16* __restrict__ wb, u16* __restrict__ wt) {
    __shared__ u16 tile[64][65];
    const int f0 = blockIdx.x * 64;
    const int d0 = blockIdx.y * 64;
    const int t  = threadIdx.x;
#pragma unroll
    for (int rep = 0; rep < 16; ++rep) {
        int idx = rep * 256 + t;
        int r = idx >> 6, c = idx & 63;
        float v = W[(size_t)(f0 + r) * DMODEL + d0 + c];
        u16 u = f2b(v);
        tile[r][c] = u;
        wb[(size_t)(f0 + r) * DMODEL + d0 + c] = u;
    }
    __syncthreads();
#pragma unroll
    for (int rep = 0; rep < 16; ++rep) {
        int idx = rep * 256 + t;
        int r = idx >> 6, c = idx & 63;
        wt[(size_t)(d0 + r) * NFEAT + f0 + c] = tile[c][r];
    }
}

// compiler-level ordering fence (no instruction) + HW barrier
#define CBAR() do { asm volatile("" ::: "memory"); __builtin_amdgcn_s_barrier(); } while (0)

// LDS tile layout (verified conflict-free r13/14): row-major [rows][64] bf16 (128 B/row);
// 1-KB chunk = 8 rows. Stage: lane -> (row 8c+lane>>3, granule (lane&7)^(lane>>3)) = full
// 128-B lines. Read: phys granule ch0 = (lhi^(lane&7))<<4, k-slice at ch0^64.

// Shared macros for the 256x128 register-prefetch pipeline (gemm1_pipe).
#define PREF(T, A0P, BP) do {                                                   \
        if ((T) < NT) {                                                         \
            const char* Abp = lds + ((T) % 3) * 32768 + wm * 16384 + l15 * 128; \
            const char* Bbp = lds + BOFF + ((T) & 1) * 16384 + wn * 4096 + l15 * 128; \
            _Pragma("unroll")                                                   \
            for (int fm = 0; fm < 4; ++fm) {                                    \
                A0P[fm][0] = *(const short8*)(Abp + fm * 2048 + ch0);           \
                A0P[fm][1] = *(const short8*)(Abp + fm * 2048 + (ch0 ^ 64));    \
            }                                                                   \
            _Pragma("unroll")                                                   \
            for (int nh = 0; nh < 2; ++nh) {                                    \
                BP[nh][0] = *(const short8*)(Bbp + nh * 2048 + ch0);            \
                BP[nh][1] = *(const short8*)(Bbp + nh * 2048 + (ch0 ^ 64));     \
            }                                                                   \
        }                                                                       \
    } while (0)

#define MMA0_(A0C, BC) do {                                                     \
        _Pragma("unroll")                                                       \
        for (int nh = 0; nh < 2; ++nh)                                          \
            _Pragma("unroll")                                                   \
            for (int ks = 0; ks < 2; ++ks)                                      \
                _Pragma("unroll")                                               \
                for (int fm = 0; fm < 4; ++fm)                                  \
                    acc[fm][nh] = __builtin_amdgcn_mfma_f32_16x16x32_bf16(      \
                        A0C[fm][ks], BC[nh][ks], acc[fm][nh], 0, 0, 0);         \
    } while (0)

#define MMA1_(BC) do {                                                          \
        _Pragma("unroll")                                                       \
        for (int nh = 0; nh < 2; ++nh)                                          \
            _Pragma("unroll")                                                   \
            for (int ks = 0; ks < 2; ++ks)                                      \
                _Pragma("unroll")                                               \
                for (int fm = 0; fm < 4; ++fm)                                  \
                    acc[4 + fm][nh] = __builtin_amdgcn_mfma_f32_16x16x32_bf16(  \
                        a1[fm][ks], BC[nh][ks], acc[4 + fm][nh], 0, 0, 0);      \
    } while (0)

#define GTILE(T, A0C, BC, A0P, BP) do {                                         \
        const char* Ab_ = lds + ((T) % 3) * 32768 + wm * 16384 + l15 * 128;     \
        _Pragma("unroll")                                                       \
        for (int fm = 0; fm < 4; ++fm) {                                        \
            a1[fm][0] = *(const short8*)(Ab_ + (4 + fm) * 2048 + ch0);          \
            a1[fm][1] = *(const short8*)(Ab_ + (4 + fm) * 2048 + (ch0 ^ 64));   \
        }                                                                       \
        STAGE_A((T) + 2);                                                       \
        __builtin_amdgcn_s_setprio(1);                                          \
        MMA0_(A0C, BC);                                                         \
        __builtin_amdgcn_s_setprio(0);                                          \
        STAGE_B((T) + 2);                                                       \
        if ((T) < NT - 2) asm volatile("s_waitcnt vmcnt(6)" ::: "memory");      \
        else              asm volatile("s_waitcnt vmcnt(0)" ::: "memory");      \
        CBAR();   /* all waves: (T+1) landed -> prefetch reads safe */          \
        PREF((T) + 1, A0P, BP);                                                 \
        __builtin_amdgcn_s_setprio(1);                                          \
        MMA1_(BC);                                                              \
        __builtin_amdgcn_s_setprio(0);                                          \
    } while (0)

// ---------------- GEMM 1: 256x128 tile, register-prefetch pipeline (round-16 best) ---------
// H = A @ B^T (bf16). Grid 256. LDS 128 KiB: A 3x32K @0, B 2x16K @98304.
__global__ __launch_bounds__(512, 2)
void gemm1_pipe(const u16* __restrict__ A, const u16* __restrict__ B,
                u16* __restrict__ H, int N, int K) {
    const int NT = K >> 6;                 // 128
    __shared__ __align__(1024) char lds[131072];
    const int BOFF = 98304;

    const int tid  = threadIdx.x;
    const int lane = tid & 63;
    const int wave = tid >> 6;
    const int wm   = wave >> 2;
    const int wn   = wave & 3;

    const int nwg = gridDim.x;
    const int swz = (blockIdx.x & 7) * (nwg >> 3) + (blockIdx.x >> 3);
    const int ntn = N >> 7;
    const int tm0 = (swz / ntn) << 8;
    const int tn0 = (swz % ntn) << 7;

    const int sr8 = lane >> 3;
    const int sg  = (lane & 7) ^ sr8;
    const int l15 = lane & 15, lhi = lane >> 4;
    const int ch0 = ((lhi ^ (lane & 7)) << 4);

    auto STAGE_A = [&](int tau) {
        if (tau < NT) {
            char* d = lds + (tau % 3) * 32768 + wave * 4096;
#pragma unroll
            for (int i = 0; i < 4; ++i)
                gld16(A + (size_t)(tm0 + wave * 32 + i * 8 + sr8) * K + ((size_t)tau << 6) + sg * 8,
                      d + i * 1024);
        }
    };
    auto STAGE_B = [&](int tau) {
        if (tau < NT) {
            char* d = lds + BOFF + (tau & 1) * 16384 + wave * 2048;
#pragma unroll
            for (int i = 0; i < 2; ++i)
                gld16(B + (size_t)(tn0 + wave * 16 + i * 8 + sr8) * K + ((size_t)tau << 6) + sg * 8,
                      d + i * 1024);
        }
    };

    short8 a0X[4][2], a0Y[4][2], a1[4][2];
    short8 bX[2][2], bY[2][2];
    f32x4  acc[8][2] = {};

    STAGE_A(0); STAGE_B(0);
    STAGE_A(1); STAGE_B(1);
    asm volatile("s_waitcnt vmcnt(6)" ::: "memory");
    __builtin_amdgcn_s_barrier();
    PREF(0, a0X, bX);

    for (int t = 0; t < NT; t += 2) {
        GTILE(t,     a0X, bX, a0Y, bY);
        GTILE(t + 1, a0Y, bY, a0X, bX);
    }
    __syncthreads();   // 1-barrier loop: sync before LDS reuse in epilogue

    // epilogue: bf16 tile via LDS transpose, coalesced 16B stores
    u16* lu = (u16*)lds;
#pragma unroll
    for (int fm = 0; fm < 8; ++fm)
#pragma unroll
        for (int nh = 0; nh < 2; ++nh) {
            const int col  = wn * 32 + nh * 16 + l15;
            const int row0 = wm * 128 + fm * 16 + lhi * 4;
#pragma unroll
            for (int r = 0; r < 4; ++r)
                lu[(row0 + r) * 128 + col] = f2b(acc[fm][nh][r]);
        }
    __syncthreads();
    const uint4* ls = (const uint4*)lds;
#pragma unroll
    for (int s = 0; s < 8; ++s) {
        int i = s * 512 + tid;
        int row = i >> 4;
        int col = (i & 15) * 8;
        *(uint4*)(H + (size_t)(tm0 + row) * N + (tn0 + col)) = ls[i];
    }
}

// ---------------- GEMM 2: persistent 1024x256 panels, relaxed-fence loop (round-16 best) ----
__global__ __launch_bounds__(512, 2)
void gemm2_persist(const u16* __restrict__ A, const u16* __restrict__ B,
                   float* __restrict__ O, const float* __restrict__ bias,
                   int N, int K) {
    __shared__ __align__(1024) char lds[163840];
    const int BOFF = 98304;
    const int TTOT = 64;

    const int tid  = threadIdx.x;
    const int lane = tid & 63;
    const int wave = tid >> 6;
    const int wm   = wave >> 2;
    const int wn   = wave & 3;

    const int bid = blockIdx.x;
    const int xcd = bid & 7;
    const int sub = (bid >> 3) & 3;
    const int mg  = bid >> 5;
    const int tn0     = ((xcd << 2) + sub) << 8;
    const int tm_base = mg << 10;

    const int sr8 = lane >> 3;
    const int sg  = (lane & 7) ^ sr8;
    const int l15 = lane & 15, lhi = lane >> 4;
    const int ch0 = ((lhi ^ (lane & 7)) << 4);

    auto STAGE_A = [&](int tau) {
        if (tau < TTOT) {
            char* d = lds + (tau % 3) * 32768 + wave * 4096;
            const int rb = tm_base + ((tau >> 4) << 8) + wave * 32 + sr8;
            const size_t co = ((size_t)(tau & 15) << 6) + sg * 8;
#pragma unroll
            for (int i = 0; i < 4; ++i)
                gld16(A + (size_t)(rb + i * 8) * K + co, d + i * 1024);
        }
    };
    auto STAGE_B = [&](int tau) {
        if (tau < TTOT) {
            char* d = lds + BOFF + (tau & 1) * 32768 + wave * 4096;
            const int rb = tn0 + wave * 32 + sr8;
            const size_t co = ((size_t)(tau & 15) << 6) + sg * 8;
#pragma unroll
            for (int i = 0; i < 4; ++i)
                gld16(B + (size_t)(rb + i * 8) * K + co, d + i * 1024);
        }
    };

    short8 a0[4][2], a1[4][2];
    short8 b[4][2];
    f32x4  acc[8][4] = {};

    const char* Ab;
    const char* Bb;
    auto LDA0 = [&] {
#pragma unroll
        for (int fm = 0; fm < 4; ++fm) {
            a0[fm][0] = *(const short8*)(Ab + fm * 2048 + ch0);
            a0[fm][1] = *(const short8*)(Ab + fm * 2048 + (ch0 ^ 64));
        }
    };
    auto LDA1 = [&] {
#pragma unroll
        for (int fm = 0; fm < 4; ++fm) {
            a1[fm][0] = *(const short8*)(Ab + (4 + fm) * 2048 + ch0);
            a1[fm][1] = *(const short8*)(Ab + (4 + fm) * 2048 + (ch0 ^ 64));
        }
    };
    auto LDB_ = [&](int nh) {
#pragma unroll
        for (int fn = 0; fn < 2; ++fn) {
            b[nh * 2 + fn][0] = *(const short8*)(Bb + (nh * 2 + fn) * 2048 + ch0);
            b[nh * 2 + fn][1] = *(const short8*)(Bb + (nh * 2 + fn) * 2048 + (ch0 ^ 64));
        }
    };
    auto MMA0 = [&](int nh) {
#pragma unroll
        for (int ks = 0; ks < 2; ++ks)
#pragma unroll
            for (int fm = 0; fm < 4; ++fm)
#pragma unroll
                for (int fn = 0; fn < 2; ++fn)
                    acc[fm][nh * 2 + fn] = __builtin_amdgcn_mfma_f32_16x16x32_bf16(
                        a0[fm][ks], b[nh * 2 + fn][ks], acc[fm][nh * 2 + fn], 0, 0, 0);
    };
    auto MMA1 = [&](int nh) {
#pragma unroll
        for (int ks = 0; ks < 2; ++ks)
#pragma unroll
            for (int fm = 0; fm < 4; ++fm)
#pragma unroll
                for (int fn = 0; fn < 2; ++fn)
                    acc[4 + fm][nh * 2 + fn] = __builtin_amdgcn_mfma_f32_16x16x32_bf16(
                        a1[fm][ks], b[nh * 2 + fn][ks], acc[4 + fm][nh * 2 + fn], 0, 0, 0);
    };

    const int ocol = tn0 + wn * 64;
    float bv[4];
#pragma unroll
    for (int fn = 0; fn < 4; ++fn) bv[fn] = bias[ocol + fn * 16 + l15];

    STAGE_A(0); STAGE_B(0);
    STAGE_A(1); STAGE_B(1);
    asm volatile("s_waitcnt vmcnt(8)" ::: "memory");
    __builtin_amdgcn_s_barrier();

    for (int tt = 0; tt < TTOT; ++tt) {
        Ab = lds + (tt % 3) * 32768 + wm * 16384 + l15 * 128;
        Bb = lds + BOFF + (tt & 1) * 32768 + wn * 8192 + l15 * 128;

        LDB_(0); LDB_(1); LDA0(); LDA1();
        STAGE_A(tt + 2);
        __builtin_amdgcn_s_setprio(1);
        MMA0(0); MMA0(1);
        __builtin_amdgcn_s_setprio(0);
        CBAR();                    // B reads drained (consumed above); safe to restage B
        STAGE_B(tt + 2);
        __builtin_amdgcn_s_setprio(1);
        MMA1(1); MMA1(0);
        __builtin_amdgcn_s_setprio(0);
        if (tt < TTOT - 2)       asm volatile("s_waitcnt vmcnt(8)" ::: "memory");
        else if (tt == TTOT - 2) asm volatile("s_waitcnt vmcnt(0)" ::: "memory");
        CBAR();

        // per-tile epilogue after the barrier: stores overlap next tile's K-loop
        if ((tt & 15) == 15) {
            const int orow = tm_base + ((tt >> 4) << 8) + wm * 128;
#pragma unroll
            for (int fm = 0; fm < 8; ++fm) {
                const int row0 = orow + fm * 16 + lhi * 4;
#pragma unroll
                for (int fn = 0; fn < 4; ++fn) {
                    const int col = ocol + fn * 16 + l15;
#pragma unroll
                    for (int r = 0; r < 4; ++r) {
                        float v = acc[fm][fn][r] + bv[fn];
                        O[(size_t)(row0 + r) * N + col] = v > 0.f ? v : 0.f;
                        acc[fm][fn][r] = 0.f;
                    }
                }
            }
        }
    }
}

// ---------------- launch ----------------

extern "C" void kernel_launch(void* const* d_in, const int* in_sizes, int n_in,
                              void* d_out, int out_size, void* d_ws, size_t ws_size,
                              hipStream_t stream) {
    const float* x    = (const float*)d_in[0];   // [8192, 8192]
    const float* W    = (const float*)d_in[1];   // [8192, 1024]
    const float* bias = (const float*)d_in[2];   // [8192]
    float* out = (float*)d_out;                  // [8192, 8192] fp32

    char* ws = (char*)d_ws;
    u16* xb = (u16*)ws;                                        // 134217728 B
    u16* wt = (u16*)(ws + 134217728);                          // [1024][8192]
    u16* wb = (u16*)(ws + 134217728 + 16777216);               // [8192][1024]
    u16* hb = (u16*)(ws + 134217728 + 2 * 16777216);           // [8192][1024]

    cvt_x_kernel<<<(BATCH * NFEAT / 8) / 256, 256, 0, stream>>>(x, xb);
    cvt_w_kernel<<<dim3(NFEAT / 64, DMODEL / 64), 256, 0, stream>>>(W, wb, wt);

    gemm1_pipe<<<dim3((BATCH / 256) * (DMODEL / 128)), 512, 0, stream>>>(
        xb, wt, hb, DMODEL, NFEAT);

    gemm2_persist<<<dim3(256), 512, 0, stream>>>(
        hb, wb, out, bias, NFEAT, DMODEL);
}